// Round 1
// baseline (190.952 us; speedup 1.0000x reference)
//
#include <hip/hip_runtime.h>

// ChunkRanker: out[n] = realism(std(chunk_n)) + 0.3*0.5 + 0.2*cosine(chunk_n[0:10,:], ctx[-10:,:])
// chunks: [4096, 128, 64] fp32, previous_context: [128, 64] fp32, out: [4096] fp32.
// Memory-bound: 134 MB read once -> ~21 us at 6.3 TB/s HBM (less if L3-warm).

#define N_CHUNKS 4096
#define CHUNK_ELEMS 8192        // 128*64
#define CHUNK_F4 2048           // 8192/4
#define START_F4 160            // first 10 rows * 64 / 4 = 640 floats = 160 float4
#define CTX_OFF_F4 1888         // (118*64)/4 — last 10 rows of previous_context

__global__ __launch_bounds__(256) void chunk_ranker_kernel(
    const float* __restrict__ chunks,
    const float* __restrict__ prev_ctx,
    float* __restrict__ out)
{
    const int n = blockIdx.x;
    const int t = threadIdx.x;
    const float4* __restrict__ c4   = (const float4*)(chunks) + (size_t)n * CHUNK_F4;
    const float4* __restrict__ ctx4 = (const float4*)(prev_ctx) + CTX_OFF_F4;

    float sum = 0.f, sumsq = 0.f, dot = 0.f, ssq = 0.f, csq = 0.f;

    #pragma unroll
    for (int i = 0; i < 8; ++i) {
        const int j = i * 256 + t;           // float4 index 0..2047, coalesced
        float4 v = c4[j];
        sum   += (v.x + v.y) + (v.z + v.w);
        sumsq += v.x*v.x + v.y*v.y + v.z*v.z + v.w*v.w;
        if (j < START_F4) {                  // only first unrolled iter diverges
            float4 c = ctx4[j];
            dot += v.x*c.x + v.y*c.y + v.z*c.z + v.w*c.w;
            ssq += v.x*v.x + v.y*v.y + v.z*v.z + v.w*v.w;
            csq += c.x*c.x + c.y*c.y + c.z*c.z + c.w*c.w;
        }
    }

    // wave-64 butterfly reduce (5 values)
    #pragma unroll
    for (int off = 32; off > 0; off >>= 1) {
        sum   += __shfl_down(sum, off);
        sumsq += __shfl_down(sumsq, off);
        dot   += __shfl_down(dot, off);
        ssq   += __shfl_down(ssq, off);
        csq   += __shfl_down(csq, off);
    }

    __shared__ float s[4][5];
    const int wave = t >> 6;
    const int lane = t & 63;
    if (lane == 0) {
        s[wave][0] = sum; s[wave][1] = sumsq; s[wave][2] = dot;
        s[wave][3] = ssq; s[wave][4] = csq;
    }
    __syncthreads();

    if (t == 0) {
        sum   = s[0][0] + s[1][0] + s[2][0] + s[3][0];
        sumsq = s[0][1] + s[1][1] + s[2][1] + s[3][1];
        dot   = s[0][2] + s[1][2] + s[2][2] + s[3][2];
        ssq   = s[0][3] + s[1][3] + s[2][3] + s[3][3];
        csq   = s[0][4] + s[1][4] + s[2][4] + s[3][4];

        const float M = (float)CHUNK_ELEMS;
        float var = (sumsq - sum * sum / M) / (M - 1.f);
        float sd  = sqrtf(fmaxf(var, 0.f));

        float realism;
        if (sd < 0.01f)      realism = sd * 10.f;
        else if (sd > 0.5f)  realism = 0.5f / sd;
        else                 realism = 1.f - fabsf(sd - 0.1f);

        float denom = fmaxf(sqrtf(ssq) * sqrtf(csq), 1e-8f);
        float boundary = dot / denom;

        out[n] = realism + 0.3f * 0.5f + 0.2f * boundary;
    }
}

extern "C" void kernel_launch(void* const* d_in, const int* in_sizes, int n_in,
                              void* d_out, int out_size, void* d_ws, size_t ws_size,
                              hipStream_t stream) {
    const float* chunks   = (const float*)d_in[0];   // [4096,128,64]
    // d_in[1] = regime_probs [9] — unused (regime_consistency is constant 0.5)
    const float* prev_ctx = (const float*)d_in[2];   // [128,64]
    float* out = (float*)d_out;                      // [4096]

    chunk_ranker_kernel<<<N_CHUNKS, 256, 0, stream>>>(chunks, prev_ctx, out);
}

// Round 2
// 190.086 us; speedup vs baseline: 1.0046x; 1.0046x over previous
//
#include <hip/hip_runtime.h>

// ChunkRanker: out[n] = realism(std(chunk_n)) + 0.15 + 0.2*cosine(chunk_n[0:10,:], ctx[-10:,:])
// chunks: [4096, 128, 64] fp32 (134 MB, read exactly once -> memory-bound floor ~20 us).
// R2: batch all 8 dwordx4 loads up front (max ILP, no branch in load clause),
//     boundary terms handled branchlessly by threads 0..159 from the already-loaded v[0].

#define N_CHUNKS 4096
#define CHUNK_ELEMS 8192        // 128*64
#define CHUNK_F4 2048           // 8192/4
#define START_F4 160            // first 10 rows * 64 floats / 4
#define CTX_OFF_F4 1888         // (118*64)/4 — last 10 rows of previous_context

__global__ __launch_bounds__(256, 8) void chunk_ranker_kernel(
    const float* __restrict__ chunks,
    const float* __restrict__ prev_ctx,
    float* __restrict__ out)
{
    const int n = blockIdx.x;
    const int t = threadIdx.x;
    const float4* __restrict__ c4   = (const float4*)(chunks) + (size_t)n * CHUNK_F4;
    const float4* __restrict__ ctx4 = (const float4*)(prev_ctx) + CTX_OFF_F4;

    // Issue all 8 global loads before any consumption (one clause, 8 in flight).
    float4 v[8];
    #pragma unroll
    for (int i = 0; i < 8; ++i) v[i] = c4[i * 256 + t];

    float sum = 0.f, sumsq = 0.f;
    #pragma unroll
    for (int i = 0; i < 8; ++i) {
        sum   += (v[i].x + v[i].y) + (v[i].z + v[i].w);
        sumsq += v[i].x*v[i].x + v[i].y*v[i].y + v[i].z*v[i].z + v[i].w*v[i].w;
    }

    // Boundary terms: float4 index t (< 160) was loaded as v[0] in iter 0.
    float dot = 0.f, ssq = 0.f, csq = 0.f;
    if (t < START_F4) {
        float4 a = v[0];
        float4 c = ctx4[t];
        dot = a.x*c.x + a.y*c.y + a.z*c.z + a.w*c.w;
        ssq = a.x*a.x + a.y*a.y + a.z*a.z + a.w*a.w;
        csq = c.x*c.x + c.y*c.y + c.z*c.z + c.w*c.w;
    }

    // wave-64 butterfly reduce (5 values)
    #pragma unroll
    for (int off = 32; off > 0; off >>= 1) {
        sum   += __shfl_down(sum, off);
        sumsq += __shfl_down(sumsq, off);
        dot   += __shfl_down(dot, off);
        ssq   += __shfl_down(ssq, off);
        csq   += __shfl_down(csq, off);
    }

    __shared__ float s[4][5];
    const int wave = t >> 6;
    const int lane = t & 63;
    if (lane == 0) {
        s[wave][0] = sum; s[wave][1] = sumsq; s[wave][2] = dot;
        s[wave][3] = ssq; s[wave][4] = csq;
    }
    __syncthreads();

    if (t == 0) {
        sum   = s[0][0] + s[1][0] + s[2][0] + s[3][0];
        sumsq = s[0][1] + s[1][1] + s[2][1] + s[3][1];
        dot   = s[0][2] + s[1][2] + s[2][2] + s[3][2];
        ssq   = s[0][3] + s[1][3] + s[2][3] + s[3][3];
        csq   = s[0][4] + s[1][4] + s[2][4] + s[3][4];

        const float M = (float)CHUNK_ELEMS;
        float var = (sumsq - sum * sum / M) / (M - 1.f);
        float sd  = sqrtf(fmaxf(var, 0.f));

        float realism;
        if (sd < 0.01f)      realism = sd * 10.f;
        else if (sd > 0.5f)  realism = 0.5f / sd;
        else                 realism = 1.f - fabsf(sd - 0.1f);

        float denom = fmaxf(sqrtf(ssq) * sqrtf(csq), 1e-8f);
        float boundary = dot / denom;

        out[n] = realism + 0.3f * 0.5f + 0.2f * boundary;
    }
}

extern "C" void kernel_launch(void* const* d_in, const int* in_sizes, int n_in,
                              void* d_out, int out_size, void* d_ws, size_t ws_size,
                              hipStream_t stream) {
    const float* chunks   = (const float*)d_in[0];   // [4096,128,64]
    // d_in[1] = regime_probs [9] — unused (regime_consistency is constant 0.5)
    const float* prev_ctx = (const float*)d_in[2];   // [128,64]
    float* out = (float*)d_out;                      // [4096]

    chunk_ranker_kernel<<<N_CHUNKS, 256, 0, stream>>>(chunks, prev_ctx, out);
}